// Round 1
// baseline (6542.709 us; speedup 1.0000x reference)
//
#include <hip/hip_runtime.h>
#include <math.h>

#define BB 1024
#define TT 50
#define MM 128
#define PP 128
#define FF 64
#define BN_EPS 1e-5f

__device__ __forceinline__ float fast_sigmoid(float x) {
    return 1.0f / (1.0f + __expf(-x));
}
__device__ __forceinline__ float fast_tanh(float x) {
    // tanh(x) = 1 - 2/(exp(2x)+1); saturates correctly for |x| large
    return 1.0f - 2.0f / (__expf(2.0f * x) + 1.0f);
}

__global__ __launch_bounds__(256) void decoder_kernel(
    const float* __restrict__ X,      // (B,T,M)
    const float* __restrict__ yprev,  // (B,T,F)
    const float* __restrict__ w1,     // (M, 2P+M) = (128,384)
    const float* __restrict__ b1,     // (128,)
    const float* __restrict__ w2,     // (1,128)
    const float* __restrict__ b2,     // (1,)
    const float* __restrict__ fcw,    // (64,192)
    const float* __restrict__ fcb,    // (64,)
    const float* __restrict__ bng,    // (64,)
    const float* __restrict__ bnb,    // (64,)
    const float* __restrict__ bnm,    // (64,)
    const float* __restrict__ bnv,    // (64,)
    const float* __restrict__ wih0,   // (512,64)
    const float* __restrict__ whh0,   // (512,128)
    const float* __restrict__ bih0,   // (512,)
    const float* __restrict__ bhh0,   // (512,)
    const float* __restrict__ wih1,   // (512,128)
    const float* __restrict__ whh1,   // (512,128)
    const float* __restrict__ bih1,   // (512,)
    const float* __restrict__ bhh1,   // (512,)
    const float* __restrict__ fcfw,   // (64,256)
    const float* __restrict__ fcfb,   // (64,)
    float* __restrict__ out)          // (B,64)
{
    // padded to 129 to break bank aliasing in the score phase (bank = (t + n) % 32)
    __shared__ float Xs[TT][MM + 1];
    __shared__ float XP[TT][MM + 1];
    __shared__ float h0[PP], c0[PP], h1[PP], c1[PP];
    __shared__ float ctx[MM], sp[MM];
    __shared__ float yt[FF], ytil[FF];
    __shared__ float sc[64];
    __shared__ float g[4 * PP];

    const int tid = threadIdx.x;
    const int b = blockIdx.x;

    // ---- load X_encoded[b] into LDS (coalesced) ----
    const float* Xb = X + (size_t)b * TT * MM;
    for (int i = tid; i < TT * MM; i += 256) {
        int t = i >> 7, m = i & 127;
        Xs[t][m] = Xb[i];
    }
    if (tid < PP) { h0[tid] = 0.f; c0[tid] = 0.f; h1[tid] = 0.f; c1[tid] = 0.f; ctx[tid] = 0.f; }
    __syncthreads();

    // ---- x_proj[b,t,n] = sum_m X[b,t,m] * w1_x[n,m]  (w1_x = w1[:, 256:384]) ----
    for (int idx = tid; idx < TT * MM; idx += 256) {
        int t = idx >> 7, n = idx & 127;
        const float4* wr = (const float4*)(w1 + n * 384 + 256);
        float acc = 0.f;
        #pragma unroll 8
        for (int m4 = 0; m4 < 32; ++m4) {
            float4 w = wr[m4];
            acc += Xs[t][4 * m4 + 0] * w.x + Xs[t][4 * m4 + 1] * w.y
                 + Xs[t][4 * m4 + 2] * w.z + Xs[t][4 * m4 + 3] * w.w;
        }
        XP[t][n] = acc;
    }
    __syncthreads();

    const float b2v = b2[0];

    for (int ts = 0; ts < TT; ++ts) {
        // ---- state_proj[n] = h1 . w1_d[n,:] + c1 . w1_c[n,:] + b1[n] ; y_t load ----
        if (tid < MM) {
            int n = tid;
            const float4* wd = (const float4*)(w1 + n * 384);
            const float4* wc = (const float4*)(w1 + n * 384 + 128);
            float acc = b1[n];
            #pragma unroll 8
            for (int k4 = 0; k4 < 32; ++k4) {
                float4 a = wd[k4];
                acc += h1[4 * k4 + 0] * a.x + h1[4 * k4 + 1] * a.y
                     + h1[4 * k4 + 2] * a.z + h1[4 * k4 + 3] * a.w;
                float4 cc = wc[k4];
                acc += c1[4 * k4 + 0] * cc.x + c1[4 * k4 + 1] * cc.y
                     + c1[4 * k4 + 2] * cc.z + c1[4 * k4 + 3] * cc.w;
            }
            sp[n] = acc;
        } else if (tid < MM + FF) {
            yt[tid - MM] = yprev[((size_t)b * TT + ts) * FF + (tid - MM)];
        }
        __syncthreads();

        // ---- score[t] = sum_n tanh(XP[t][n] + sp[n]) * w2[n] + b2 ----
        {
            int t = tid >> 2, q = tid & 3;
            float part = 0.f;
            if (t < TT) {
                #pragma unroll 8
                for (int n = 0; n < 32; ++n) {
                    int nn = q * 32 + n;
                    part += fast_tanh(XP[t][nn] + sp[nn]) * w2[nn];
                }
            }
            part += __shfl_xor(part, 1);
            part += __shfl_xor(part, 2);
            if (t < TT && q == 0) sc[t] = part + b2v;
        }
        __syncthreads();

        // ---- softmax over 50 scores (wave 0) ----
        if (tid < 64) {
            float v = (tid < TT) ? sc[tid] : -1e30f;
            float mx = v;
            for (int o = 32; o; o >>= 1) mx = fmaxf(mx, __shfl_xor(mx, o));
            float e = (tid < TT) ? __expf(v - mx) : 0.f;
            float s = e;
            for (int o = 32; o; o >>= 1) s += __shfl_xor(s, o);
            if (tid < TT) sc[tid] = e / s;
        }
        __syncthreads();

        // ---- context[m] = sum_t beta[t] * X[t][m] ----
        if (tid < MM) {
            float acc = 0.f;
            #pragma unroll
            for (int t = 0; t < TT; ++t) acc += sc[t] * Xs[t][tid];
            ctx[tid] = acc;
        }
        __syncthreads();

        // ---- z = [ctx, y_t] @ fc_w.T + fc_b ; batchnorm ----
        if (tid < FF) {
            int f = tid;
            const float4* wr = (const float4*)(fcw + f * 192);
            float acc = fcb[f];
            #pragma unroll 8
            for (int j4 = 0; j4 < 32; ++j4) {
                float4 w = wr[j4];
                acc += ctx[4 * j4 + 0] * w.x + ctx[4 * j4 + 1] * w.y
                     + ctx[4 * j4 + 2] * w.z + ctx[4 * j4 + 3] * w.w;
            }
            #pragma unroll 8
            for (int j4 = 0; j4 < 16; ++j4) {
                float4 w = wr[32 + j4];
                acc += yt[4 * j4 + 0] * w.x + yt[4 * j4 + 1] * w.y
                     + yt[4 * j4 + 2] * w.z + yt[4 * j4 + 3] * w.w;
            }
            ytil[f] = (acc - bnm[f]) * rsqrtf(bnv[f] + BN_EPS) * bng[f] + bnb[f];
        }
        __syncthreads();

        // ---- LSTM0 gates: g[j] = ytil . wih0[j,:] + h0 . whh0[j,:] + biases ----
        for (int j = tid; j < 4 * PP; j += 256) {
            const float4* wi = (const float4*)(wih0 + j * FF);
            float acc = bih0[j] + bhh0[j];
            #pragma unroll 8
            for (int k4 = 0; k4 < 16; ++k4) {
                float4 w = wi[k4];
                acc += ytil[4 * k4 + 0] * w.x + ytil[4 * k4 + 1] * w.y
                     + ytil[4 * k4 + 2] * w.z + ytil[4 * k4 + 3] * w.w;
            }
            const float4* wh = (const float4*)(whh0 + j * PP);
            #pragma unroll 8
            for (int k4 = 0; k4 < 32; ++k4) {
                float4 w = wh[k4];
                acc += h0[4 * k4 + 0] * w.x + h0[4 * k4 + 1] * w.y
                     + h0[4 * k4 + 2] * w.z + h0[4 * k4 + 3] * w.w;
            }
            g[j] = acc;
        }
        __syncthreads();

        // ---- LSTM0 update ----
        if (tid < PP) {
            int k = tid;
            float ig = fast_sigmoid(g[k]);
            float fg = fast_sigmoid(g[PP + k]);
            float gg = fast_tanh(g[2 * PP + k]);
            float og = fast_sigmoid(g[3 * PP + k]);
            float cn = fg * c0[k] + ig * gg;
            c0[k] = cn;
            h0[k] = og * fast_tanh(cn);
        }
        __syncthreads();

        // ---- LSTM1 gates: g[j] = h0 . wih1[j,:] + h1 . whh1[j,:] + biases ----
        for (int j = tid; j < 4 * PP; j += 256) {
            const float4* wi = (const float4*)(wih1 + j * PP);
            const float4* wh = (const float4*)(whh1 + j * PP);
            float acc = bih1[j] + bhh1[j];
            #pragma unroll 8
            for (int k4 = 0; k4 < 32; ++k4) {
                float4 wa = wi[k4];
                acc += h0[4 * k4 + 0] * wa.x + h0[4 * k4 + 1] * wa.y
                     + h0[4 * k4 + 2] * wa.z + h0[4 * k4 + 3] * wa.w;
                float4 wb = wh[k4];
                acc += h1[4 * k4 + 0] * wb.x + h1[4 * k4 + 1] * wb.y
                     + h1[4 * k4 + 2] * wb.z + h1[4 * k4 + 3] * wb.w;
            }
            g[j] = acc;
        }
        __syncthreads();

        // ---- LSTM1 update ----
        if (tid < PP) {
            int k = tid;
            float ig = fast_sigmoid(g[k]);
            float fg = fast_sigmoid(g[PP + k]);
            float gg = fast_tanh(g[2 * PP + k]);
            float og = fast_sigmoid(g[3 * PP + k]);
            float cn = fg * c1[k] + ig * gg;
            c1[k] = cn;
            h1[k] = og * fast_tanh(cn);
        }
        __syncthreads();
    }

    // ---- y_pred = relu([h1, ctx] @ fcf_w.T + fcf_b) ----
    if (tid < FF) {
        int f = tid;
        const float4* wr = (const float4*)(fcfw + f * 256);
        float acc = fcfb[f];
        #pragma unroll 8
        for (int k4 = 0; k4 < 32; ++k4) {
            float4 w = wr[k4];
            acc += h1[4 * k4 + 0] * w.x + h1[4 * k4 + 1] * w.y
                 + h1[4 * k4 + 2] * w.z + h1[4 * k4 + 3] * w.w;
        }
        #pragma unroll 8
        for (int k4 = 0; k4 < 32; ++k4) {
            float4 w = wr[32 + k4];
            acc += ctx[4 * k4 + 0] * w.x + ctx[4 * k4 + 1] * w.y
                 + ctx[4 * k4 + 2] * w.z + ctx[4 * k4 + 3] * w.w;
        }
        out[(size_t)b * FF + f] = fmaxf(acc, 0.f);
    }
}

extern "C" void kernel_launch(void* const* d_in, const int* in_sizes, int n_in,
                              void* d_out, int out_size, void* d_ws, size_t ws_size,
                              hipStream_t stream) {
    (void)in_sizes; (void)n_in; (void)d_ws; (void)ws_size; (void)out_size;
    const float* X    = (const float*)d_in[0];
    const float* yp   = (const float*)d_in[1];
    const float* w1   = (const float*)d_in[2];
    const float* b1   = (const float*)d_in[3];
    const float* w2   = (const float*)d_in[4];
    const float* b2   = (const float*)d_in[5];
    const float* fcw  = (const float*)d_in[6];
    const float* fcb  = (const float*)d_in[7];
    const float* bng  = (const float*)d_in[8];
    const float* bnb  = (const float*)d_in[9];
    const float* bnm  = (const float*)d_in[10];
    const float* bnv  = (const float*)d_in[11];
    const float* wih0 = (const float*)d_in[12];
    const float* whh0 = (const float*)d_in[13];
    const float* bih0 = (const float*)d_in[14];
    const float* bhh0 = (const float*)d_in[15];
    const float* wih1 = (const float*)d_in[16];
    const float* whh1 = (const float*)d_in[17];
    const float* bih1 = (const float*)d_in[18];
    const float* bhh1 = (const float*)d_in[19];
    const float* fcfw = (const float*)d_in[20];
    const float* fcfb = (const float*)d_in[21];
    float* out = (float*)d_out;

    decoder_kernel<<<dim3(BB), dim3(256), 0, stream>>>(
        X, yp, w1, b1, w2, b2, fcw, fcb, bng, bnb, bnm, bnv,
        wih0, whh0, bih0, bhh0, wih1, whh1, bih1, bhh1, fcfw, fcfb, out);
}

// Round 2
// 2069.700 us; speedup vs baseline: 3.1612x; 3.1612x over previous
//
#include <hip/hip_runtime.h>
#include <math.h>

#define TT 50
#define MM 128
#define PP 128
#define FF 64
#define NB 4
#define NTHR 512
#define BN_EPS 1e-5f

__device__ __forceinline__ float fsig(float x)  { return 1.0f / (1.0f + __expf(-x)); }
__device__ __forceinline__ float ftanh(float x) { return 1.0f - 2.0f / (__expf(2.0f * x) + 1.0f); }

__device__ __forceinline__ float dot4(float4 a, float4 b) {
    return a.x * b.x + a.y * b.y + a.z * b.z + a.w * b.w;
}

__global__ __launch_bounds__(NTHR, 2) void decoder_kernel(
    const float* __restrict__ X,      // (B,T,M)
    const float* __restrict__ yprev,  // (B,T,F)
    const float* __restrict__ w1,     // (128,384)  [w1_d | w1_c | w1_x]
    const float* __restrict__ b1,
    const float* __restrict__ w2,     // (1,128)
    const float* __restrict__ b2,
    const float* __restrict__ fcw,    // (64,192)
    const float* __restrict__ fcb,
    const float* __restrict__ bng,
    const float* __restrict__ bnb,
    const float* __restrict__ bnm,
    const float* __restrict__ bnv,
    const float* __restrict__ wih0,   // (512,64)
    const float* __restrict__ whh0,   // (512,128)
    const float* __restrict__ bih0,
    const float* __restrict__ bhh0,
    const float* __restrict__ wih1,   // (512,128)
    const float* __restrict__ whh1,   // (512,128)
    const float* __restrict__ bih1,
    const float* __restrict__ bhh1,
    const float* __restrict__ fcfw,   // (64,256)
    const float* __restrict__ fcfb,
    float* __restrict__ out)          // (B,64)
{
    // pads: +4 keeps float4 alignment AND splits the 4 bb-slices across bank groups
    __shared__ __align__(16) float Xs[NB][TT][MM + 4];     // 105,600 B
    __shared__ __align__(16) float sp[NB][MM + 4];
    __shared__ __align__(16) float h0s[2][NB][PP + 4];     // ping-pong
    __shared__ __align__(16) float h1s[2][NB][PP + 4];
    __shared__ __align__(16) float c0s[NB][PP + 4], c1s[NB][PP + 4];
    __shared__ __align__(16) float ctxs[NB][MM + 4];
    __shared__ __align__(16) float yts[NB][FF + 4], ytils[NB][FF + 4];
    __shared__ float scs[NB][68];
    __shared__ float w2s[MM];

    const int tid = threadIdx.x;
    const int b0 = blockIdx.x * NB;

    // ---- prologue: X tile -> LDS (float4, coalesced), zero states ----
    for (int i4 = tid; i4 < NB * TT * 32; i4 += NTHR) {
        int bb = i4 / (TT * 32);
        int r  = i4 % (TT * 32);
        int t = r >> 5, m4 = r & 31;
        float4 v = ((const float4*)(X + (size_t)(b0 + bb) * TT * MM))[r];
        *(float4*)&Xs[bb][t][m4 * 4] = v;
    }
    for (int i = tid; i < NB * (PP + 4); i += NTHR) {
        int bb = i / (PP + 4), k = i % (PP + 4);
        h0s[0][bb][k] = 0.f; h0s[1][bb][k] = 0.f;
        h1s[0][bb][k] = 0.f; h1s[1][bb][k] = 0.f;
        c0s[bb][k] = 0.f;    c1s[bb][k] = 0.f;
    }
    if (tid < MM) w2s[tid] = w2[tid];
    __syncthreads();

    // ---- x_proj in registers: owner thread (bq, tq, qq) holds xp[n], n = qq*64.. ----
    const int rr = tid & 127;
    const int bq = tid >> 7;               // batch slot 0..3 (wave-uniform-ish)
    const bool own = rr < 2 * TT;          // 100 owners per batch slot
    const int tq = rr >> 1, qq = rr & 1;

    float xp[64];
    #pragma unroll
    for (int n = 0; n < 64; ++n) xp[n] = 0.f;
    if (own) {
        for (int m4 = 0; m4 < 32; ++m4) {
            float4 xv = *(const float4*)&Xs[bq][tq][m4 * 4];
            #pragma unroll
            for (int n = 0; n < 64; ++n) {
                float4 w = *(const float4*)(w1 + (size_t)(qq * 64 + n) * 384 + 256 + m4 * 4);
                xp[n] += dot4(xv, w);
            }
        }
    }

    // ---- hoisted per-thread constants ----
    const float b2v = b2[0];
    const int nq  = tid >> 2;              // 0..127 (row / cell index)
    const int bbq = tid & 3;               // batch slot for quad-shared weights
    const float b1v = b1[nq];
    // lstm0 bias sums (cell nq)
    const float bi0 = bih0[nq] + bhh0[nq];
    const float bf0 = bih0[PP + nq] + bhh0[PP + nq];
    const float bg0 = bih0[2 * PP + nq] + bhh0[2 * PP + nq];
    const float bo0 = bih0[3 * PP + nq] + bhh0[3 * PP + nq];
    const float bi1 = bih1[nq] + bhh1[nq];
    const float bf1 = bih1[PP + nq] + bhh1[PP + nq];
    const float bg1 = bih1[2 * PP + nq] + bhh1[2 * PP + nq];
    const float bo1 = bih1[3 * PP + nq] + bhh1[3 * PP + nq];
    // fc + bn constants (f = tid>>2 when tid<256)
    float fck1 = 0.f, fck0 = 0.f;
    if (tid < 256) {
        int f = tid >> 2;
        fck1 = rsqrtf(bnv[f] + BN_EPS) * bng[f];
        fck0 = bnb[f] - bnm[f] * fck1 + fcb[f] * fck1;  // ytil = z*fck1 + (bnb - (bnm-fcb)*k1)... careful below
        // recompute properly: ytil = (z + fcb - bnm)*k1 + bnb -> z*k1 + (fcb-bnm)*k1 + bnb
        fck0 = (fcb[f] - bnm[f]) * fck1 + bnb[f];
    }

    for (int ts = 0; ts < TT; ++ts) {
        const int p = ts & 1;

        // ---- A: state_proj[bb][n] = w1_d[n,:].h1 + w1_c[n,:].c1 + b1 ----
        {
            const float* wd = w1 + (size_t)nq * 384;
            float a1 = 0.f, a2 = 0.f;
            #pragma unroll 8
            for (int k4 = 0; k4 < 32; ++k4) {
                float4 w = *(const float4*)(wd + k4 * 4);
                float4 h = *(const float4*)&h1s[p][bbq][k4 * 4];
                a1 += dot4(w, h);
                float4 wc = *(const float4*)(wd + 128 + k4 * 4);
                float4 c = *(const float4*)&c1s[bbq][k4 * 4];
                a2 += dot4(wc, c);
            }
            sp[bbq][nq] = a1 + a2 + b1v;
        }
        __syncthreads();

        // ---- B: score[t] = sum_n tanh(xp + sp) * w2 ----
        if (own) {
            float acc = 0.f;
            #pragma unroll
            for (int n = 0; n < 64; ++n)
                acc += ftanh(xp[n] + sp[bq][qq * 64 + n]) * w2s[qq * 64 + n];
            acc += __shfl_xor(acc, 1);
            if (qq == 0) scs[bq][tq] = acc + b2v;
        }
        __syncthreads();

        // ---- C: softmax over 50 (one wave per batch slot) + y_t load ----
        if (tid < 256) {
            int b = tid >> 6, t = tid & 63;
            float v = (t < TT) ? scs[b][t] : -1e30f;
            float mx = v;
            #pragma unroll
            for (int o = 32; o; o >>= 1) mx = fmaxf(mx, __shfl_xor(mx, o));
            float e = (t < TT) ? __expf(v - mx) : 0.f;
            float s = e;
            #pragma unroll
            for (int o = 32; o; o >>= 1) s += __shfl_xor(s, o);
            if (t < TT) scs[b][t] = e / s;
        } else {
            int i = tid - 256; int bb = i >> 6, f = i & 63;
            yts[bb][f] = yprev[((size_t)(b0 + bb) * TT + ts) * FF + f];
        }
        __syncthreads();

        // ---- D: context[m] = sum_t beta[t]*X[t][m] ----
        {
            int b = tid >> 7, m = tid & 127;
            float acc = 0.f;
            #pragma unroll
            for (int t = 0; t < TT; ++t) acc += scs[b][t] * Xs[b][t][m];
            ctxs[b][m] = acc;
        }
        __syncthreads();

        // ---- E: fc + batchnorm ----
        if (tid < 256) {
            int f = tid >> 2, bb = tid & 3;
            const float* wr = fcw + (size_t)f * 192;
            float a1 = 0.f, a2 = 0.f;
            #pragma unroll 8
            for (int j4 = 0; j4 < 32; ++j4) {
                float4 w = *(const float4*)(wr + j4 * 4);
                float4 cx = *(const float4*)&ctxs[bb][j4 * 4];
                a1 += dot4(w, cx);
            }
            #pragma unroll 8
            for (int j4 = 0; j4 < 16; ++j4) {
                float4 w = *(const float4*)(wr + 128 + j4 * 4);
                float4 yv = *(const float4*)&yts[bb][j4 * 4];
                a2 += dot4(w, yv);
            }
            ytils[bb][f] = (a1 + a2) * fck1 + fck0;
        }
        __syncthreads();

        // ---- F+U0: lstm0 gates (4 rows per thread, 4 bb share weights) + update ----
        {
            const int k = nq, bb = bbq;
            float ai = bi0, af = bf0, ag = bg0, ao = bo0;
            #pragma unroll 4
            for (int k4 = 0; k4 < 16; ++k4) {
                float4 x  = *(const float4*)&ytils[bb][k4 * 4];
                float4 wi = *(const float4*)(wih0 + (size_t)k * FF + k4 * 4);
                float4 wf = *(const float4*)(wih0 + (size_t)(PP + k) * FF + k4 * 4);
                float4 wg = *(const float4*)(wih0 + (size_t)(2 * PP + k) * FF + k4 * 4);
                float4 wo = *(const float4*)(wih0 + (size_t)(3 * PP + k) * FF + k4 * 4);
                ai += dot4(x, wi); af += dot4(x, wf); ag += dot4(x, wg); ao += dot4(x, wo);
            }
            #pragma unroll 4
            for (int k4 = 0; k4 < 32; ++k4) {
                float4 h  = *(const float4*)&h0s[p][bb][k4 * 4];
                float4 wi = *(const float4*)(whh0 + (size_t)k * PP + k4 * 4);
                float4 wf = *(const float4*)(whh0 + (size_t)(PP + k) * PP + k4 * 4);
                float4 wg = *(const float4*)(whh0 + (size_t)(2 * PP + k) * PP + k4 * 4);
                float4 wo = *(const float4*)(whh0 + (size_t)(3 * PP + k) * PP + k4 * 4);
                ai += dot4(h, wi); af += dot4(h, wf); ag += dot4(h, wg); ao += dot4(h, wo);
            }
            float ii = fsig(ai), ff_ = fsig(af), gg = ftanh(ag), oo = fsig(ao);
            float cn = ff_ * c0s[bb][k] + ii * gg;
            c0s[bb][k] = cn;
            h0s[p ^ 1][bb][k] = oo * ftanh(cn);
        }
        __syncthreads();

        // ---- G+U1: lstm1 gates + update (x = new h0, h = old h1) ----
        {
            const int k = nq, bb = bbq;
            float ai = bi1, af = bf1, ag = bg1, ao = bo1;
            #pragma unroll 4
            for (int k4 = 0; k4 < 32; ++k4) {
                float4 x  = *(const float4*)&h0s[p ^ 1][bb][k4 * 4];
                float4 wi = *(const float4*)(wih1 + (size_t)k * PP + k4 * 4);
                float4 wf = *(const float4*)(wih1 + (size_t)(PP + k) * PP + k4 * 4);
                float4 wg = *(const float4*)(wih1 + (size_t)(2 * PP + k) * PP + k4 * 4);
                float4 wo = *(const float4*)(wih1 + (size_t)(3 * PP + k) * PP + k4 * 4);
                ai += dot4(x, wi); af += dot4(x, wf); ag += dot4(x, wg); ao += dot4(x, wo);
            }
            #pragma unroll 4
            for (int k4 = 0; k4 < 32; ++k4) {
                float4 h  = *(const float4*)&h1s[p][bb][k4 * 4];
                float4 wi = *(const float4*)(whh1 + (size_t)k * PP + k4 * 4);
                float4 wf = *(const float4*)(whh1 + (size_t)(PP + k) * PP + k4 * 4);
                float4 wg = *(const float4*)(whh1 + (size_t)(2 * PP + k) * PP + k4 * 4);
                float4 wo = *(const float4*)(whh1 + (size_t)(3 * PP + k) * PP + k4 * 4);
                ai += dot4(h, wi); af += dot4(h, wf); ag += dot4(h, wg); ao += dot4(h, wo);
            }
            float ii = fsig(ai), ff_ = fsig(af), gg = ftanh(ag), oo = fsig(ao);
            float cn = ff_ * c1s[bb][k] + ii * gg;
            c1s[bb][k] = cn;
            h1s[p ^ 1][bb][k] = oo * ftanh(cn);
        }
        __syncthreads();
    }

    // ---- y_pred = relu([h1, ctx] @ fcf_w.T + fcf_b); last h1 side = TT&1 = 0 ----
    if (tid < 256) {
        int f = tid >> 2, bb = tid & 3;
        const float* wr = fcfw + (size_t)f * 256;
        float a1 = 0.f, a2 = 0.f;
        #pragma unroll 8
        for (int k4 = 0; k4 < 32; ++k4) {
            float4 w = *(const float4*)(wr + k4 * 4);
            float4 h = *(const float4*)&h1s[TT & 1][bb][k4 * 4];
            a1 += dot4(w, h);
        }
        #pragma unroll 8
        for (int k4 = 0; k4 < 32; ++k4) {
            float4 w = *(const float4*)(wr + 128 + k4 * 4);
            float4 c = *(const float4*)&ctxs[bb][k4 * 4];
            a2 += dot4(w, c);
        }
        out[(size_t)(b0 + bb) * FF + f] = fmaxf(a1 + a2 + fcfb[f], 0.f);
    }
}

extern "C" void kernel_launch(void* const* d_in, const int* in_sizes, int n_in,
                              void* d_out, int out_size, void* d_ws, size_t ws_size,
                              hipStream_t stream) {
    (void)in_sizes; (void)n_in; (void)d_ws; (void)ws_size; (void)out_size;
    const float* X    = (const float*)d_in[0];
    const float* yp   = (const float*)d_in[1];
    const float* w1   = (const float*)d_in[2];
    const float* b1   = (const float*)d_in[3];
    const float* w2   = (const float*)d_in[4];
    const float* b2   = (const float*)d_in[5];
    const float* fcw  = (const float*)d_in[6];
    const float* fcb  = (const float*)d_in[7];
    const float* bng  = (const float*)d_in[8];
    const float* bnb  = (const float*)d_in[9];
    const float* bnm  = (const float*)d_in[10];
    const float* bnv  = (const float*)d_in[11];
    const float* wih0 = (const float*)d_in[12];
    const float* whh0 = (const float*)d_in[13];
    const float* bih0 = (const float*)d_in[14];
    const float* bhh0 = (const float*)d_in[15];
    const float* wih1 = (const float*)d_in[16];
    const float* whh1 = (const float*)d_in[17];
    const float* bih1 = (const float*)d_in[18];
    const float* bhh1 = (const float*)d_in[19];
    const float* fcfw = (const float*)d_in[20];
    const float* fcfb = (const float*)d_in[21];
    float* out = (float*)d_out;

    decoder_kernel<<<dim3(1024 / NB), dim3(NTHR), 0, stream>>>(
        X, yp, w1, b1, w2, b2, fcw, fcb, bng, bnb, bnm, bnv,
        wih0, whh0, bih0, bhh0, wih1, whh1, bih1, bhh1, fcfw, fcfb, out);
}